// Round 22
// baseline (94.197 us; speedup 1.0000x reference)
//
#include <hip/hip_runtime.h>
#include <stdint.h>

#define T_SEQ 2048
#define NB 2
#define NH 16
#define HD 64
#define HID 1024
#define MTOK (NB * T_SEQ)   // 4096

typedef float f32x4 __attribute__((ext_vector_type(4)));
typedef float f32x16 __attribute__((ext_vector_type(16)));
typedef short bf16x8 __attribute__((ext_vector_type(8)));
typedef unsigned short u16;
typedef unsigned int u32;

// scale = (1/sqrt(64)) * log2(e), folded into q so softmax uses exp2
#define QSCALE 0.1803368801f

__device__ __forceinline__ u16 f2bf(float f) {
  union { float f; uint32_t u; } v; v.f = f;
  return (u16)((v.u + 0x7fffu + ((v.u >> 16) & 1u)) >> 16);
}

__device__ __forceinline__ void gl_lds16(const void* g, void* l) {
  __builtin_amdgcn_global_load_lds(
      (const __attribute__((address_space(1))) unsigned int*)g,
      (__attribute__((address_space(3))) unsigned int*)l, 16, 0, 0);
}

// ------- fused preprocessing: convert x -> bf16  +  transpose/convert both weights -------
__global__ __launch_bounds__(256)
void prep_k(const float* __restrict__ x, u16* __restrict__ xb,
            const float* __restrict__ wa, u16* __restrict__ waT,
            const float* __restrict__ wp, u16* __restrict__ wpT) {
  __shared__ float tile[32][33];
  const int bid = blockIdx.x, tid = threadIdx.x;
  if (bid < 1024) {
    int i = bid * 1024 + tid;
#pragma unroll
    for (int it = 0; it < 4; ++it, i += 256) {
      float4 f = ((const float4*)x)[i];
      ushort4 o;
      o.x = f2bf(f.x); o.y = f2bf(f.y); o.z = f2bf(f.z); o.w = f2bf(f.w);
      ((ushort4*)xb)[i] = o;
    }
    return;
  }
  const float* in;
  u16* out;
  int R, C, c0, r0;
  if (bid < 4096) {
    const int j = bid - 1024;
    in = wa; out = waT; R = HID; C = 3 * HID;
    c0 = (j % 96) * 32; r0 = (j / 96) * 32;
  } else {
    const int j = bid - 4096;
    in = wp; out = wpT; R = HID; C = HID;
    c0 = (j % 32) * 32; r0 = (j / 32) * 32;
  }
  const int tx = tid & 31, ty = tid >> 5;  // 32 x 8
#pragma unroll
  for (int i = 0; i < 32; i += 8)
    tile[ty + i][tx] = in[(size_t)(r0 + ty + i) * C + c0 + tx];
  __syncthreads();
#pragma unroll
  for (int i = 0; i < 32; i += 8)
    out[(size_t)(c0 + ty + i) * R + r0 + tx] = f2bf(tile[tx][ty + i]);
}

// ---------------- GEMM1: qkv.  128x128 tile, BK=64, 8 waves x (64x32), dbuf LDS (64KB) ----------------
__global__ __launch_bounds__(512, 4)
void gemm_k(const u16* __restrict__ A, const u16* __restrict__ Bt,
            const float* __restrict__ bias,
            u16* __restrict__ q, u16* __restrict__ kk, u16* __restrict__ v) {
  __shared__ __align__(16) char lds[65536];   // 2 x (A 16KB + B 16KB)
  const int tid = threadIdx.x, wid = tid >> 6, lane = tid & 63;
  const int bid = blockIdx.y * 24 + blockIdx.x;   // 0..767
  const int xcd = bid & 7, idx = bid >> 3;        // idx 0..95 within region
  const int m0 = ((xcd >> 1) * 8 + idx / 12) * 128;
  const int n0 = ((xcd & 1) * 12 + idx % 12) * 128;
  const int wm = (wid >> 2) * 64, wn = (wid & 3) * 32;

  f32x4 acc[4][2];
  const f32x4 z = {0.f, 0.f, 0.f, 0.f};
#pragma unroll
  for (int mi = 0; mi < 4; ++mi)
#pragma unroll
    for (int ni = 0; ni < 2; ++ni) acc[mi][ni] = z;

  const int srow = tid >> 3;                          // 0..63 (call adds +64)
  const int scsrc = ((((tid & 7) << 4) ^ ((srow & 7) << 4)) >> 1);  // pre-swizzled src (elems)
  const int rA = lane & 15;
  const int kg16 = (lane >> 4) << 4;                  // frag k-group byte offset (0/16/32/48)

#define GSTAGE(tt_)                                                                     \
  do {                                                                                  \
    const int k0_ = (tt_) << 6;                                                         \
    char* base_ = lds + (((tt_) & 1) << 15);                                            \
    gl_lds16(A + (size_t)(m0 + srow) * HID + k0_ + scsrc, base_ + wid * 1024);          \
    gl_lds16(A + (size_t)(m0 + 64 + srow) * HID + k0_ + scsrc, base_ + 8192 + wid * 1024); \
    gl_lds16(Bt + (size_t)(n0 + srow) * HID + k0_ + scsrc, base_ + 16384 + wid * 1024); \
    gl_lds16(Bt + (size_t)(n0 + 64 + srow) * HID + k0_ + scsrc, base_ + 24576 + wid * 1024); \
  } while (0)

  GSTAGE(0);
  GSTAGE(1);

  for (int tt = 0; tt < 16; ++tt) {
    if (tt < 15) asm volatile("s_waitcnt vmcnt(4)" ::: "memory");  // step tt landed; tt+1 in flight
    else         asm volatile("s_waitcnt vmcnt(0)" ::: "memory");
    __builtin_amdgcn_s_barrier();
    __builtin_amdgcn_sched_barrier(0);

    const char* ab = lds + ((tt & 1) << 15);
    const char* bb = ab + 16384;
#pragma unroll
    for (int ks = 0; ks < 2; ++ks) {
      bf16x8 a[4], b[2];
#pragma unroll
      for (int mi = 0; mi < 4; ++mi) {
        const int row = wm + mi * 16 + rA;
        a[mi] = *(const bf16x8*)(ab + row * 128 + ((ks * 64 + kg16) ^ ((row & 7) << 4)));
      }
#pragma unroll
      for (int ni = 0; ni < 2; ++ni) {
        const int row = wn + ni * 16 + rA;
        b[ni] = *(const bf16x8*)(bb + row * 128 + ((ks * 64 + kg16) ^ ((row & 7) << 4)));
      }
#pragma unroll
      for (int mi = 0; mi < 4; ++mi)
#pragma unroll
        for (int ni = 0; ni < 2; ++ni)
          acc[mi][ni] = __builtin_amdgcn_mfma_f32_16x16x32_bf16(a[mi], b[ni], acc[mi][ni], 0, 0, 0);
    }

    __builtin_amdgcn_s_barrier();
    __builtin_amdgcn_sched_barrier(0);
    if (tt + 2 < 16) GSTAGE(tt + 2);   // buffer tt&1 is free now
  }
#undef GSTAGE

  const int coll = lane & 15, rowl = (lane >> 4) << 2;
  const int reg = n0 >> 10;          // block-uniform: 0=q, 1=k, 2=v
  const int bb2 = m0 >> 11;          // block-uniform batch
  const int tloc = (m0 & 2047) + wm; // t base for this wave
  if (reg == 2) {
    // V^T (B,H,D,T): pack 4 consecutive t into one 8B store
#pragma unroll
    for (int mi = 0; mi < 4; ++mi) {
#pragma unroll
      for (int ni = 0; ni < 2; ++ni) {
        const int n = n0 + wn + ni * 16 + coll;
        const float bv = bias[n];
        const int c = n & 1023, h = c >> 6, d = c & 63;
        ushort4 pk;
        pk.x = f2bf(acc[mi][ni][0] + bv);
        pk.y = f2bf(acc[mi][ni][1] + bv);
        pk.z = f2bf(acc[mi][ni][2] + bv);
        pk.w = f2bf(acc[mi][ni][3] + bv);
        const int t0 = tloc + mi * 16 + rowl;
        *(ushort4*)(v + ((size_t)(bb2 * NH + h) * HD + d) * T_SEQ + t0) = pk;
      }
    }
  } else {
    u16* dst = (reg == 0) ? q : kk;
    const float sc = (reg == 0) ? QSCALE : 1.0f;
#pragma unroll
    for (int mi = 0; mi < 4; ++mi) {
#pragma unroll
      for (int ni = 0; ni < 2; ++ni) {
        const int n = n0 + wn + ni * 16 + coll;
        const float bv = bias[n];
        const int c = n & 1023, h = c >> 6, d = c & 63;
#pragma unroll
        for (int r = 0; r < 4; ++r) {
          const int t = tloc + mi * 16 + rowl + r;
          dst[((size_t)(bb2 * NH + h) * T_SEQ + t) * HD + d] = f2bf((acc[mi][ni][r] + bv) * sc);
        }
      }
    }
  }
}

// ---------------- GEMM2 (proj): 64x128 tile, BK=64, 8 waves x (32x32), dbuf LDS (48KB) ----------------
__global__ __launch_bounds__(512, 6)
void gemm2_k(const u16* __restrict__ A, const u16* __restrict__ Bt,
             const float* __restrict__ bias, float* __restrict__ outf) {
  __shared__ __align__(16) char lds[49152];   // 2 x (A 8KB + B 16KB)
  const int tid = threadIdx.x, wid = tid >> 6, lane = tid & 63;
  const int m0 = blockIdx.y * 64, n0 = blockIdx.x * 128;
  const int wm = (wid >> 2) * 32, wn = (wid & 3) * 32;

  f32x4 acc[2][2];
  const f32x4 z = {0.f, 0.f, 0.f, 0.f};
#pragma unroll
  for (int mi = 0; mi < 2; ++mi)
#pragma unroll
    for (int ni = 0; ni < 2; ++ni) acc[mi][ni] = z;

  const int srow = tid >> 3;                          // 0..63
  const int scsrc = ((((tid & 7) << 4) ^ ((srow & 7) << 4)) >> 1);
  const int rA = lane & 15;
  const int kg16 = (lane >> 4) << 4;

#define G2STAGE(tt_)                                                                    \
  do {                                                                                  \
    const int k0_ = (tt_) << 6;                                                         \
    char* base_ = lds + (((tt_) & 1) ? 24576 : 0);                                      \
    gl_lds16(A + (size_t)(m0 + srow) * HID + k0_ + scsrc, base_ + wid * 1024);          \
    gl_lds16(Bt + (size_t)(n0 + srow) * HID + k0_ + scsrc, base_ + 8192 + wid * 1024);  \
    gl_lds16(Bt + (size_t)(n0 + 64 + srow) * HID + k0_ + scsrc, base_ + 16384 + wid * 1024); \
  } while (0)

  G2STAGE(0);
  G2STAGE(1);

  for (int tt = 0; tt < 16; ++tt) {
    if (tt < 15) asm volatile("s_waitcnt vmcnt(3)" ::: "memory");
    else         asm volatile("s_waitcnt vmcnt(0)" ::: "memory");
    __builtin_amdgcn_s_barrier();
    __builtin_amdgcn_sched_barrier(0);

    const char* ab = lds + ((tt & 1) ? 24576 : 0);
    const char* bb = ab + 8192;
#pragma unroll
    for (int ks = 0; ks < 2; ++ks) {
      bf16x8 a[2], b[2];
#pragma unroll
      for (int mi = 0; mi < 2; ++mi) {
        const int row = wm + mi * 16 + rA;
        a[mi] = *(const bf16x8*)(ab + row * 128 + ((ks * 64 + kg16) ^ ((row & 7) << 4)));
      }
#pragma unroll
      for (int ni = 0; ni < 2; ++ni) {
        const int row = wn + ni * 16 + rA;
        b[ni] = *(const bf16x8*)(bb + row * 128 + ((ks * 64 + kg16) ^ ((row & 7) << 4)));
      }
#pragma unroll
      for (int mi = 0; mi < 2; ++mi)
#pragma unroll
        for (int ni = 0; ni < 2; ++ni)
          acc[mi][ni] = __builtin_amdgcn_mfma_f32_16x16x32_bf16(a[mi], b[ni], acc[mi][ni], 0, 0, 0);
    }

    __builtin_amdgcn_s_barrier();
    __builtin_amdgcn_sched_barrier(0);
    if (tt + 2 < 16) G2STAGE(tt + 2);
  }
#undef G2STAGE

  const int coll = lane & 15, rowl = (lane >> 4) << 2;
#pragma unroll
  for (int mi = 0; mi < 2; ++mi) {
#pragma unroll
    for (int ni = 0; ni < 2; ++ni) {
      const int n = n0 + wn + ni * 16 + coll;
      const float bv = bias[n];
#pragma unroll
      for (int r = 0; r < 4; ++r) {
        const int m = m0 + wm + mi * 16 + rowl + r;
        outf[(size_t)m * HID + n] = acc[mi][ni][r] + bv;
      }
    }
  }
}

// -------- attention helper: lane-local online softmax + P->bf16 B-frag pack (per 32-row set) --------
__device__ __forceinline__ void smxpack(f32x16& s0, f32x16& s1, float& m, float& l,
                                        f32x16& ot0, f32x16& ot1, bf16x8* fr, bool hi) {
  float mx[16];
#pragma unroll
  for (int i = 0; i < 16; ++i) mx[i] = fmaxf(s0[i], s1[i]);
#pragma unroll
  for (int d = 8; d; d >>= 1)
#pragma unroll
    for (int i = 0; i < d; ++i) mx[i] = fmaxf(mx[i], mx[i + d]);
  const float tm = fmaxf(mx[0], __shfl_xor(mx[0], 32, 64));
  // defer-max: only rescale when the running max grew by > 4 (P bounded by 2^4)
  if (!__all(tm <= m + 4.0f)) {
    const float mnew = fmaxf(m, tm);
    const float fold = __builtin_amdgcn_exp2f(m - mnew);
    m = mnew;
    l *= fold;
#pragma unroll
    for (int i = 0; i < 16; ++i) { ot0[i] *= fold; ot1[i] *= fold; }
  }
#pragma unroll
  for (int i = 0; i < 16; ++i) {
    s0[i] = __builtin_amdgcn_exp2f(s0[i] - m);
    s1[i] = __builtin_amdgcn_exp2f(s1[i] - m);
  }
  float sm[16];
#pragma unroll
  for (int i = 0; i < 16; ++i) sm[i] = s0[i] + s1[i];
#pragma unroll
  for (int d = 8; d; d >>= 1)
#pragma unroll
    for (int i = 0; i < d; ++i) sm[i] += sm[i + d];
  l += sm[0] + __shfl_xor(sm[0], 32, 64);

  u32 w0[8], w1[8];
#pragma unroll
  for (int mm = 0; mm < 8; ++mm) {
    asm("v_cvt_pk_bf16_f32 %0, %1, %2" : "=v"(w0[mm]) : "v"(s0[2 * mm]), "v"(s0[2 * mm + 1]));
    asm("v_cvt_pk_bf16_f32 %0, %1, %2" : "=v"(w1[mm]) : "v"(s1[2 * mm]), "v"(s1[2 * mm + 1]));
  }
#pragma unroll
  for (int sb = 0; sb < 2; ++sb) {
#pragma unroll
    for (int t = 0; t < 2; ++t) {
      u32 a0 = sb ? w1[4 * t]     : w0[4 * t];
      u32 a1 = sb ? w1[4 * t + 1] : w0[4 * t + 1];
      u32 a2 = sb ? w1[4 * t + 2] : w0[4 * t + 2];
      u32 a3 = sb ? w1[4 * t + 3] : w0[4 * t + 3];
      u32 snd0 = hi ? a0 : a2;
      u32 snd1 = hi ? a1 : a3;
      u32 own0 = hi ? a2 : a0;
      u32 own1 = hi ? a3 : a1;
      u32 p0 = __shfl_xor(snd0, 32, 64);
      u32 p1 = __shfl_xor(snd1, 32, 64);
      union { u32 u[4]; bf16x8 v; } t2;
      t2.u[0] = hi ? p0 : own0;   // j0..3  <- h_src = 0
      t2.u[1] = hi ? p1 : own1;
      t2.u[2] = hi ? own0 : p0;   // j4..7  <- h_src = 1
      t2.u[3] = hi ? own1 : p1;
      fr[sb * 2 + t] = t2.v;
    }
  }
}

// ---------------- flash attention: 128 q-rows/block, 4 waves x 64 rows (2 sets), kv-parity ----------------
// LDS-throughput fix: each wave reads K/V tile ONCE and feeds TWO 32-row QK/PV passes ->
// LDS bytes per (row x tile) halve (512 -> 256 B).  Wave (qsub in 0..1, par): rows
// [q0+64*qsub, +64), tiles tt&1==par.  Ring-4 64KB, counted vmcnt(8).  launch_bounds (256,2):
// VGPR cap 256 (est ~190 live; round-12 spill watchpoint).
__global__ __launch_bounds__(256, 2)
void attn_k(const u16* __restrict__ Q, const u16* __restrict__ K,
            const u16* __restrict__ Vt, u16* __restrict__ AO) {
  // [0,32768): K ring x4 (8KB); [32768,65536): V ring x4.  Combine/epilogue: 4 x 8448B regions.
  __shared__ __align__(16) char lds[65536];
  const int tid = threadIdx.x;
  const int lane = tid & 63;
  const int wid = tid >> 6;           // 0..3
  const int qsub = wid & 1, par = wid >> 1;
  const int bid = blockIdx.x;
  // pairing (uniform work per CU pair) + XCD grouping: xcd hosts heads {4x..4x+3}
  const int halfg = bid >> 8, r8 = bid & 255;
  const int bh = (r8 & 7) * 4 + ((r8 >> 3) & 3);
  const int lvl = r8 >> 5;                 // 0..7
  const int qb = halfg ? lvl : (15 - lvl); // CU gets (15-lvl) + (lvl): uniform
  const int q0 = qb * 128;
  const int ql = lane & 31, h = lane >> 5;
  const bool hi = (h != 0);

  const u16* Qg = Q + (size_t)bh * T_SEQ * HD;
  const u16* Kg = K + (size_t)bh * T_SEQ * HD;
  const u16* Vg = Vt + (size_t)bh * T_SEQ * HD;  // (D, T) per (b,h)

  const int q0w = q0 + qsub * 64;
  const int dq = 2 * qb + qsub;   // diagonal tile for this wave's 64 rows

  // Q fragments for both 32-row sets (B-operand): row q, k = d = s*16 + h*8 + j
  bf16x8 qfA[4], qfB[4];
#pragma unroll
  for (int s = 0; s < 4; ++s) {
    qfA[s] = *(const bf16x8*)(Qg + (size_t)(q0w + ql) * HD + s * 16 + h * 8);
    qfB[s] = *(const bf16x8*)(Qg + (size_t)(q0w + 32 + ql) * HD + s * 16 + h * 8);
  }

  f32x16 otA0, otA1, otB0, otB1;
#pragma unroll
  for (int i = 0; i < 16; ++i) { otA0[i] = 0.f; otA1[i] = 0.f; otB0[i] = 0.f; otB1[i] = 0.f; }
  float mA = -3.0e38f, lA = 0.f, mB = -3.0e38f, lB = 0.f;

  // staging geometry: 256 threads cover 32 rows x 128B per call; row = tid>>3, colbyte = (tid&7)<<4
  const int srow = tid >> 3;            // 0..31
  const int sc0 = ((((tid & 7) << 4) ^ ((srow & 7) << 4)) >> 1);  // pre-swizzled source elems

  const int nsup = qb + 1;              // supersteps; tiles nt = 2*qb+2

#define STAGE(tt_)                                                            \
  do {                                                                        \
    const int kv0_ = (tt_) << 6;                                              \
    char* kb_ = lds + (((tt_) & 3) << 13);                                    \
    char* vb_ = lds + 32768 + (((tt_) & 3) << 13);                            \
    gl_lds16(Kg + (size_t)(kv0_ + srow) * HD + sc0, kb_ + wid * 1024);        \
    gl_lds16(Kg + (size_t)(kv0_ + 32 + srow) * HD + sc0, kb_ + 4096 + wid * 1024); \
    gl_lds16(Vg + (size_t)srow * T_SEQ + kv0_ + sc0, vb_ + wid * 1024);       \
    gl_lds16(Vg + (size_t)(32 + srow) * T_SEQ + kv0_ + sc0, vb_ + 4096 + wid * 1024); \
  } while (0)

  STAGE(0);
  STAGE(1);

  for (int ss = 0; ss < nsup; ++ss) {
    if (ss + 1 < nsup) {
      STAGE(2 * ss + 2);
      STAGE(2 * ss + 3);
      asm volatile("s_waitcnt vmcnt(8)" ::: "memory");  // this superstep's 8 landed
    } else {
      asm volatile("s_waitcnt vmcnt(0)" ::: "memory");
    }
    __builtin_amdgcn_s_barrier();
    __builtin_amdgcn_sched_barrier(0);

    const int tt = 2 * ss + par;
    if (tt <= dq) {
      const int kv0 = tt << 6;
      const char* kb = lds + ((tt & 3) << 13);
      const char* vb = lds + 32768 + ((tt & 3) << 13);
      // K fragments read ONCE, feed both sets
      bf16x8 kf0[4], kf1[4];
#pragma unroll
      for (int s = 0; s < 4; ++s) {
        const int cb = 32 * s + 16 * h;
        const int r0 = ql, r1 = 32 + ql;
        kf0[s] = *(const bf16x8*)(kb + r0 * 128 + (cb ^ ((r0 & 7) << 4)));
        kf1[s] = *(const bf16x8*)(kb + r1 * 128 + (cb ^ ((r1 & 7) << 4)));
      }
      f32x16 sA0, sA1, sB0, sB1;
#pragma unroll
      for (int i = 0; i < 16; ++i) { sA0[i] = 0.f; sA1[i] = 0.f; sB0[i] = 0.f; sB1[i] = 0.f; }
      __builtin_amdgcn_s_setprio(1);
#pragma unroll
      for (int s = 0; s < 4; ++s) {
        sA0 = __builtin_amdgcn_mfma_f32_32x32x16_bf16(kf0[s], qfA[s], sA0, 0, 0, 0);
        sA1 = __builtin_amdgcn_mfma_f32_32x32x16_bf16(kf1[s], qfA[s], sA1, 0, 0, 0);
      }
#pragma unroll
      for (int s = 0; s < 4; ++s) {
        sB0 = __builtin_amdgcn_mfma_f32_32x32x16_bf16(kf0[s], qfB[s], sB0, 0, 0, 0);
        sB1 = __builtin_amdgcn_mfma_f32_32x32x16_bf16(kf1[s], qfB[s], sB1, 0, 0, 0);
      }
      __builtin_amdgcn_s_setprio(0);
      if (tt == dq) {  // causal mask on the diagonal tile (both sets live in this tile)
        const int qgA = q0w + ql, qgB = q0w + 32 + ql;
#pragma unroll
        for (int r = 0; r < 16; ++r) {
          const int kvl = (r & 3) + 8 * (r >> 2) + 4 * h;
          if (kv0 + kvl > qgA) sA0[r] = -3.0e38f;
          if (kv0 + 32 + kvl > qgA) sA1[r] = -3.0e38f;
          if (kv0 + kvl > qgB) sB0[r] = -3.0e38f;
          if (kv0 + 32 + kvl > qgB) sB1[r] = -3.0e38f;
        }
      }
      bf16x8 frA[4], frB[4];
      smxpack(sA0, sA1, mA, lA, otA0, otA1, frA, hi);
      smxpack(sB0, sB1, mB, lB, otB0, otB1, frB, hi);
      // V fragments read ONCE, feed both sets
      bf16x8 vf0[4], vf1[4];
#pragma unroll
      for (int s = 0; s < 4; ++s) {
        const int cb = 32 * s + 16 * h;
        const int r0 = ql, r1 = 32 + ql;
        vf0[s] = *(const bf16x8*)(vb + r0 * 128 + (cb ^ ((r0 & 7) << 4)));
        vf1[s] = *(const bf16x8*)(vb + r1 * 128 + (cb ^ ((r1 & 7) << 4)));
      }
      __builtin_amdgcn_s_setprio(1);
#pragma unroll
      for (int s = 0; s < 4; ++s) {
        otA0 = __builtin_amdgcn_mfma_f32_32x32x16_bf16(vf0[s], frA[s], otA0, 0, 0, 0);
        otA1 = __builtin_amdgcn_mfma_f32_32x32x16_bf16(vf1[s], frA[s], otA1, 0, 0, 0);
      }
#pragma unroll
      for (int s = 0; s < 4; ++s) {
        otB0 = __builtin_amdgcn_mfma_f32_32x32x16_bf16(vf0[s], frB[s], otB0, 0, 0, 0);
        otB1 = __builtin_amdgcn_mfma_f32_32x32x16_bf16(vf1[s], frB[s], otB1, 0, 0, 0);
      }
      __builtin_amdgcn_s_setprio(0);
    }
    __builtin_amdgcn_s_barrier();
    __builtin_amdgcn_sched_barrier(0);
  }
#undef STAGE

  // ---- combine wave pairs (par 1 -> par 0) via LDS: region (qsub*2+set) = [32 q][66 f32] ----
  if (par == 1) {
#pragma unroll
    for (int set = 0; set < 2; ++set) {
      float* R = (float*)(lds + (qsub * 2 + set) * 8448);
      const f32x16& o0 = set ? otB0 : otA0;
      const f32x16& o1 = set ? otB1 : otA1;
#pragma unroll
      for (int r = 0; r < 16; ++r) {
        const int dl = (r & 3) + 8 * (r >> 2) + 4 * h;
        R[ql * 66 + dl] = o0[r];
        R[ql * 66 + 32 + dl] = o1[r];
      }
      if (!hi) { R[ql * 66 + 64] = set ? mB : mA; R[ql * 66 + 65] = set ? lB : lA; }
    }
  }
  __builtin_amdgcn_s_barrier();
  if (par == 1) return;

  const int bb = bh >> 4, hh = bh & 15;
  const int r2 = lane >> 3;          // row within 8
  const int c8 = (lane & 7) * 8;     // d-chunk start

  auto finish = [&](int set, float m_, float l_, const f32x16& o0, const f32x16& o1) {
    float* R = (float*)(lds + (qsub * 2 + set) * 8448);
    const float m2 = R[ql * 66 + 64];
    const float l2 = R[ql * 66 + 65];
    const float M = fmaxf(m_, m2);
    const float c1 = __builtin_amdgcn_exp2f(m_ - M);
    const float c2 = __builtin_amdgcn_exp2f(m2 - M);
    const float L = c1 * l_ + c2 * l2;
    const float inv = 1.0f / L;
    float of0[16], of1[16];
#pragma unroll
    for (int r = 0; r < 16; ++r) {
      const int dl = (r & 3) + 8 * (r >> 2) + 4 * h;
      of0[r] = (c1 * o0[r] + c2 * R[ql * 66 + dl]) * inv;
      of1[r] = (c1 * o1[r] + c2 * R[ql * 66 + 32 + dl]) * inv;
    }
    asm volatile("s_waitcnt lgkmcnt(0)" ::: "memory");
    __builtin_amdgcn_sched_barrier(0);
    // per-wave LDS transpose ([64 d][33 q] f32) -> coalesced 16B stores
    float* E = R;
#pragma unroll
    for (int r = 0; r < 16; ++r) {
      const int dl = (r & 3) + 8 * (r >> 2) + 4 * h;
      E[dl * 33 + ql] = of0[r];
      E[(dl + 32) * 33 + ql] = of1[r];
    }
    asm volatile("s_waitcnt lgkmcnt(0)" ::: "memory");
    __builtin_amdgcn_sched_barrier(0);
#pragma unroll
    for (int g = 0; g < 4; ++g) {
      const int qrow = g * 8 + r2;
      union { u16 a[8]; bf16x8 v; } ov;
#pragma unroll
      for (int j = 0; j < 8; ++j) ov.a[j] = f2bf(E[(c8 + j) * 33 + qrow]);
      *(bf16x8*)(AO + (size_t)(bb * T_SEQ + q0 + qsub * 64 + set * 32 + qrow) * HID + hh * HD + c8) = ov.v;
    }
  };
  finish(0, mA, lA, otA0, otA1);
  finish(1, mB, lB, otB0, otB1);
}

extern "C" void kernel_launch(void* const* d_in, const int* in_sizes, int n_in,
                              void* d_out, int out_size, void* d_ws, size_t ws_size,
                              hipStream_t stream) {
  const float* x      = (const float*)d_in[0];
  const float* w_attn = (const float*)d_in[1];
  const float* b_attn = (const float*)d_in[2];
  const float* w_proj = (const float*)d_in[3];
  const float* b_proj = (const float*)d_in[4];
  float* out = (float*)d_out;

  char* ws = (char*)d_ws;
  u16* xb   = (u16*)(ws);                       // 8 MB  (4096 x 1024)
  u16* wabT = (u16*)(ws + (size_t)(8  << 20));  // 6 MB  (3072 x 1024)
  u16* wpbT = (u16*)(ws + (size_t)(14 << 20));  // 2 MB  (1024 x 1024)
  u16* q    = (u16*)(ws + (size_t)(16 << 20));  // 8 MB  (B,H,T,D)
  u16* k    = (u16*)(ws + (size_t)(24 << 20));  // 8 MB  (B,H,T,D)
  u16* v    = (u16*)(ws + (size_t)(32 << 20));  // 8 MB  (B,H,D,T)  transposed!
  u16* ao   = (u16*)(ws + (size_t)(40 << 20));  // 8 MB  (B,T,C)

  prep_k<<<dim3(5120), dim3(256), 0, stream>>>(x, xb, w_attn, wabT, w_proj, wpbT);
  gemm_k<<<dim3(24, 32), dim3(512), 0, stream>>>(xb, wabT, b_attn, q, k, v);
  attn_k<<<dim3(512), dim3(256), 0, stream>>>(q, k, v, ao);
  gemm2_k<<<dim3(8, 64), dim3(512), 0, stream>>>(ao, wpbT, b_proj, out);
}

// Round 23
// 88.992 us; speedup vs baseline: 1.0585x; 1.0585x over previous
//
#include <hip/hip_runtime.h>
#include <stdint.h>

#define T_SEQ 2048
#define NB 2
#define NH 16
#define HD 64
#define HID 1024
#define MTOK (NB * T_SEQ)   // 4096

typedef float f32x4 __attribute__((ext_vector_type(4)));
typedef float f32x16 __attribute__((ext_vector_type(16)));
typedef short bf16x8 __attribute__((ext_vector_type(8)));
typedef unsigned short u16;
typedef unsigned int u32;

// scale = (1/sqrt(64)) * log2(e), folded into q so softmax uses exp2
#define QSCALE 0.1803368801f

__device__ __forceinline__ u16 f2bf(float f) {
  union { float f; uint32_t u; } v; v.f = f;
  return (u16)((v.u + 0x7fffu + ((v.u >> 16) & 1u)) >> 16);
}

__device__ __forceinline__ void gl_lds16(const void* g, void* l) {
  __builtin_amdgcn_global_load_lds(
      (const __attribute__((address_space(1))) unsigned int*)g,
      (__attribute__((address_space(3))) unsigned int*)l, 16, 0, 0);
}

// ------- fused preprocessing: convert x -> bf16  +  transpose/convert both weights -------
__global__ __launch_bounds__(256)
void prep_k(const float* __restrict__ x, u16* __restrict__ xb,
            const float* __restrict__ wa, u16* __restrict__ waT,
            const float* __restrict__ wp, u16* __restrict__ wpT) {
  __shared__ float tile[32][33];
  const int bid = blockIdx.x, tid = threadIdx.x;
  if (bid < 1024) {
    int i = bid * 1024 + tid;
#pragma unroll
    for (int it = 0; it < 4; ++it, i += 256) {
      float4 f = ((const float4*)x)[i];
      ushort4 o;
      o.x = f2bf(f.x); o.y = f2bf(f.y); o.z = f2bf(f.z); o.w = f2bf(f.w);
      ((ushort4*)xb)[i] = o;
    }
    return;
  }
  const float* in;
  u16* out;
  int R, C, c0, r0;
  if (bid < 4096) {
    const int j = bid - 1024;
    in = wa; out = waT; R = HID; C = 3 * HID;
    c0 = (j % 96) * 32; r0 = (j / 96) * 32;
  } else {
    const int j = bid - 4096;
    in = wp; out = wpT; R = HID; C = HID;
    c0 = (j % 32) * 32; r0 = (j / 32) * 32;
  }
  const int tx = tid & 31, ty = tid >> 5;  // 32 x 8
#pragma unroll
  for (int i = 0; i < 32; i += 8)
    tile[ty + i][tx] = in[(size_t)(r0 + ty + i) * C + c0 + tx];
  __syncthreads();
#pragma unroll
  for (int i = 0; i < 32; i += 8)
    out[(size_t)(c0 + ty + i) * R + r0 + tx] = f2bf(tile[tx][ty + i]);
}

// ---------------- GEMM1: qkv.  128x128 tile, BK=64, 8 waves x (64x32), dbuf LDS (64KB) ----------------
// BK=64 -> 128B LDS rows -> full 8-slot (row&7)<<4 XOR: conflict-free ds_read_b128.
// 16 K-steps, counted vmcnt(4).  L2-region XCD mapping (FETCH 37->27 MB).
__global__ __launch_bounds__(512, 4)
void gemm_k(const u16* __restrict__ A, const u16* __restrict__ Bt,
            const float* __restrict__ bias,
            u16* __restrict__ q, u16* __restrict__ kk, u16* __restrict__ v) {
  __shared__ __align__(16) char lds[65536];   // 2 x (A 16KB + B 16KB)
  const int tid = threadIdx.x, wid = tid >> 6, lane = tid & 63;
  const int bid = blockIdx.y * 24 + blockIdx.x;   // 0..767
  const int xcd = bid & 7, idx = bid >> 3;        // idx 0..95 within region
  const int m0 = ((xcd >> 1) * 8 + idx / 12) * 128;
  const int n0 = ((xcd & 1) * 12 + idx % 12) * 128;
  const int wm = (wid >> 2) * 64, wn = (wid & 3) * 32;

  f32x4 acc[4][2];
  const f32x4 z = {0.f, 0.f, 0.f, 0.f};
#pragma unroll
  for (int mi = 0; mi < 4; ++mi)
#pragma unroll
    for (int ni = 0; ni < 2; ++ni) acc[mi][ni] = z;

  const int srow = tid >> 3;                          // 0..63 (call adds +64)
  const int scsrc = ((((tid & 7) << 4) ^ ((srow & 7) << 4)) >> 1);  // pre-swizzled src (elems)
  const int rA = lane & 15;
  const int kg16 = (lane >> 4) << 4;                  // frag k-group byte offset (0/16/32/48)

#define GSTAGE(tt_)                                                                     \
  do {                                                                                  \
    const int k0_ = (tt_) << 6;                                                         \
    char* base_ = lds + (((tt_) & 1) << 15);                                            \
    gl_lds16(A + (size_t)(m0 + srow) * HID + k0_ + scsrc, base_ + wid * 1024);          \
    gl_lds16(A + (size_t)(m0 + 64 + srow) * HID + k0_ + scsrc, base_ + 8192 + wid * 1024); \
    gl_lds16(Bt + (size_t)(n0 + srow) * HID + k0_ + scsrc, base_ + 16384 + wid * 1024); \
    gl_lds16(Bt + (size_t)(n0 + 64 + srow) * HID + k0_ + scsrc, base_ + 24576 + wid * 1024); \
  } while (0)

  GSTAGE(0);
  GSTAGE(1);

  for (int tt = 0; tt < 16; ++tt) {
    if (tt < 15) asm volatile("s_waitcnt vmcnt(4)" ::: "memory");  // step tt landed; tt+1 in flight
    else         asm volatile("s_waitcnt vmcnt(0)" ::: "memory");
    __builtin_amdgcn_s_barrier();
    __builtin_amdgcn_sched_barrier(0);

    const char* ab = lds + ((tt & 1) << 15);
    const char* bb = ab + 16384;
#pragma unroll
    for (int ks = 0; ks < 2; ++ks) {
      bf16x8 a[4], b[2];
#pragma unroll
      for (int mi = 0; mi < 4; ++mi) {
        const int row = wm + mi * 16 + rA;
        a[mi] = *(const bf16x8*)(ab + row * 128 + ((ks * 64 + kg16) ^ ((row & 7) << 4)));
      }
#pragma unroll
      for (int ni = 0; ni < 2; ++ni) {
        const int row = wn + ni * 16 + rA;
        b[ni] = *(const bf16x8*)(bb + row * 128 + ((ks * 64 + kg16) ^ ((row & 7) << 4)));
      }
#pragma unroll
      for (int mi = 0; mi < 4; ++mi)
#pragma unroll
        for (int ni = 0; ni < 2; ++ni)
          acc[mi][ni] = __builtin_amdgcn_mfma_f32_16x16x32_bf16(a[mi], b[ni], acc[mi][ni], 0, 0, 0);
    }

    __builtin_amdgcn_s_barrier();
    __builtin_amdgcn_sched_barrier(0);
    if (tt + 2 < 16) GSTAGE(tt + 2);   // buffer tt&1 is free now
  }
#undef GSTAGE

  const int coll = lane & 15, rowl = (lane >> 4) << 2;
  const int reg = n0 >> 10;          // block-uniform: 0=q, 1=k, 2=v
  const int bb2 = m0 >> 11;          // block-uniform batch
  const int tloc = (m0 & 2047) + wm; // t base for this wave
  if (reg == 2) {
    // V^T (B,H,D,T): pack 4 consecutive t into one 8B store
#pragma unroll
    for (int mi = 0; mi < 4; ++mi) {
#pragma unroll
      for (int ni = 0; ni < 2; ++ni) {
        const int n = n0 + wn + ni * 16 + coll;
        const float bv = bias[n];
        const int c = n & 1023, h = c >> 6, d = c & 63;
        ushort4 pk;
        pk.x = f2bf(acc[mi][ni][0] + bv);
        pk.y = f2bf(acc[mi][ni][1] + bv);
        pk.z = f2bf(acc[mi][ni][2] + bv);
        pk.w = f2bf(acc[mi][ni][3] + bv);
        const int t0 = tloc + mi * 16 + rowl;
        *(ushort4*)(v + ((size_t)(bb2 * NH + h) * HD + d) * T_SEQ + t0) = pk;
      }
    }
  } else {
    u16* dst = (reg == 0) ? q : kk;
    const float sc = (reg == 0) ? QSCALE : 1.0f;
#pragma unroll
    for (int mi = 0; mi < 4; ++mi) {
#pragma unroll
      for (int ni = 0; ni < 2; ++ni) {
        const int n = n0 + wn + ni * 16 + coll;
        const float bv = bias[n];
        const int c = n & 1023, h = c >> 6, d = c & 63;
#pragma unroll
        for (int r = 0; r < 4; ++r) {
          const int t = tloc + mi * 16 + rowl + r;
          dst[((size_t)(bb2 * NH + h) * T_SEQ + t) * HD + d] = f2bf((acc[mi][ni][r] + bv) * sc);
        }
      }
    }
  }
}

// ---------------- GEMM2 (proj): 64x128 tile, BK=64, 8 waves x (32x32), dbuf LDS (48KB) ----------------
__global__ __launch_bounds__(512, 6)
void gemm2_k(const u16* __restrict__ A, const u16* __restrict__ Bt,
             const float* __restrict__ bias, float* __restrict__ outf) {
  __shared__ __align__(16) char lds[49152];   // 2 x (A 8KB + B 16KB)
  const int tid = threadIdx.x, wid = tid >> 6, lane = tid & 63;
  const int m0 = blockIdx.y * 64, n0 = blockIdx.x * 128;
  const int wm = (wid >> 2) * 32, wn = (wid & 3) * 32;

  f32x4 acc[2][2];
  const f32x4 z = {0.f, 0.f, 0.f, 0.f};
#pragma unroll
  for (int mi = 0; mi < 2; ++mi)
#pragma unroll
    for (int ni = 0; ni < 2; ++ni) acc[mi][ni] = z;

  const int srow = tid >> 3;                          // 0..63
  const int scsrc = ((((tid & 7) << 4) ^ ((srow & 7) << 4)) >> 1);
  const int rA = lane & 15;
  const int kg16 = (lane >> 4) << 4;

#define G2STAGE(tt_)                                                                    \
  do {                                                                                  \
    const int k0_ = (tt_) << 6;                                                         \
    char* base_ = lds + (((tt_) & 1) ? 24576 : 0);                                      \
    gl_lds16(A + (size_t)(m0 + srow) * HID + k0_ + scsrc, base_ + wid * 1024);          \
    gl_lds16(Bt + (size_t)(n0 + srow) * HID + k0_ + scsrc, base_ + 8192 + wid * 1024);  \
    gl_lds16(Bt + (size_t)(n0 + 64 + srow) * HID + k0_ + scsrc, base_ + 16384 + wid * 1024); \
  } while (0)

  G2STAGE(0);
  G2STAGE(1);

  for (int tt = 0; tt < 16; ++tt) {
    if (tt < 15) asm volatile("s_waitcnt vmcnt(3)" ::: "memory");
    else         asm volatile("s_waitcnt vmcnt(0)" ::: "memory");
    __builtin_amdgcn_s_barrier();
    __builtin_amdgcn_sched_barrier(0);

    const char* ab = lds + ((tt & 1) ? 24576 : 0);
    const char* bb = ab + 8192;
#pragma unroll
    for (int ks = 0; ks < 2; ++ks) {
      bf16x8 a[2], b[2];
#pragma unroll
      for (int mi = 0; mi < 2; ++mi) {
        const int row = wm + mi * 16 + rA;
        a[mi] = *(const bf16x8*)(ab + row * 128 + ((ks * 64 + kg16) ^ ((row & 7) << 4)));
      }
#pragma unroll
      for (int ni = 0; ni < 2; ++ni) {
        const int row = wn + ni * 16 + rA;
        b[ni] = *(const bf16x8*)(bb + row * 128 + ((ks * 64 + kg16) ^ ((row & 7) << 4)));
      }
#pragma unroll
      for (int mi = 0; mi < 2; ++mi)
#pragma unroll
        for (int ni = 0; ni < 2; ++ni)
          acc[mi][ni] = __builtin_amdgcn_mfma_f32_16x16x32_bf16(a[mi], b[ni], acc[mi][ni], 0, 0, 0);
    }

    __builtin_amdgcn_s_barrier();
    __builtin_amdgcn_sched_barrier(0);
    if (tt + 2 < 16) G2STAGE(tt + 2);
  }
#undef G2STAGE

  const int coll = lane & 15, rowl = (lane >> 4) << 2;
#pragma unroll
  for (int mi = 0; mi < 2; ++mi) {
#pragma unroll
    for (int ni = 0; ni < 2; ++ni) {
      const int n = n0 + wn + ni * 16 + coll;
      const float bv = bias[n];
#pragma unroll
      for (int r = 0; r < 4; ++r) {
        const int m = m0 + wm + mi * 16 + rowl + r;
        outf[(size_t)m * HID + n] = acc[mi][ni][r] + bv;
      }
    }
  }
}

// ---------------- flash attention: 128 q-rows/block, 8 waves, 2-way kv-parity split ----------------
// Ring-4 LDS (64KB, 2 blk/CU): both next tiles staged at the superstep TOP -> 2-tile prefetch.
// launch_bounds (512,4): VGPR allocator must not cap below ~72 (round-12 spill lesson).
__global__ __launch_bounds__(512, 4)
void attn_k(const u16* __restrict__ Q, const u16* __restrict__ K,
            const u16* __restrict__ Vt, u16* __restrict__ AO) {
  // [0,32768): K ring x4 (8KB); [32768,65536): V ring x4.  Combine/epilogue reuse [0,33792).
  __shared__ __align__(16) char lds[65536];
  const int tid = threadIdx.x;
  const int lane = tid & 63;
  const int wid = tid >> 6;           // 0..7
  const int qsub = wid & 3, par = wid >> 2;
  const int bid = blockIdx.x;
  // pairing (uniform work per CU pair) + XCD grouping: xcd hosts heads {4x..4x+3}
  const int halfg = bid >> 8, r8 = bid & 255;
  const int bh = (r8 & 7) * 4 + ((r8 >> 3) & 3);
  const int lvl = r8 >> 5;                 // 0..7
  const int qb = halfg ? lvl : (15 - lvl); // CU gets (15-lvl) + (lvl): uniform
  const int q0 = qb * 128;
  const int ql = lane & 31, h = lane >> 5;
  const bool hi = (h != 0);

  const u16* Qg = Q + (size_t)bh * T_SEQ * HD;
  const u16* Kg = K + (size_t)bh * T_SEQ * HD;
  const u16* Vg = Vt + (size_t)bh * T_SEQ * HD;  // (D, T) per (b,h)

  const int q0w = q0 + qsub * 32;
  const int dq = 2 * qb + (qsub >> 1);   // this wave-pair's diagonal tile

  // Q fragments (B-operand): row q = lane&31, k = d = s*16 + h*8 + j
  bf16x8 qf[4];
#pragma unroll
  for (int s = 0; s < 4; ++s)
    qf[s] = *(const bf16x8*)(Qg + (size_t)(q0w + ql) * HD + s * 16 + h * 8);

  f32x16 ot0, ot1;
#pragma unroll
  for (int i = 0; i < 16; ++i) { ot0[i] = 0.f; ot1[i] = 0.f; }
  float m = -3.0e38f, l = 0.f;

  // staging geometry: thread t covers tile byte [t*16, t*16+16): row = t>>3, colbyte = (t&7)<<4
  const int srow = tid >> 3;            // 0..63
  const int scb = (tid & 7) << 4;
  const int sc0 = (scb ^ ((srow & 7) << 4)) >> 1;  // pre-swizzled source elem offset

  const int nsup = qb + 1;              // supersteps; tiles nt = 2*qb+2

#define STAGE(tt_)                                                            \
  do {                                                                        \
    const int kv0_ = (tt_) << 6;                                              \
    gl_lds16(Kg + (size_t)(kv0_ + srow) * HD + sc0,                           \
             lds + (((tt_) & 3) << 13) + wid * 1024);                         \
    gl_lds16(Vg + (size_t)srow * T_SEQ + kv0_ + sc0,                          \
             lds + 32768 + (((tt_) & 3) << 13) + wid * 1024);                 \
  } while (0)

  STAGE(0);
  STAGE(1);

  for (int ss = 0; ss < nsup; ++ss) {
    if (ss + 1 < nsup) {
      STAGE(2 * ss + 2);
      STAGE(2 * ss + 3);
      asm volatile("s_waitcnt vmcnt(4)" ::: "memory");  // this superstep's 4 landed
    } else {
      asm volatile("s_waitcnt vmcnt(0)" ::: "memory");
    }
    __builtin_amdgcn_s_barrier();
    __builtin_amdgcn_sched_barrier(0);

    const int tt = 2 * ss + par;
    if (tt <= dq) {
      const int kv0 = tt << 6;
      const char* kb = lds + ((tt & 3) << 13);
      const char* vb = lds + 32768 + ((tt & 3) << 13);
      // S^T[kv][q]: A = K rows (kv), B = Q rows (q)
      f32x16 s0, s1;
#pragma unroll
      for (int i = 0; i < 16; ++i) { s0[i] = 0.f; s1[i] = 0.f; }
      __builtin_amdgcn_s_setprio(1);
#pragma unroll
      for (int s = 0; s < 4; ++s) {
        const int cb = 32 * s + 16 * h;
        const int r0 = ql, r1 = 32 + ql;
        bf16x8 kf0 = *(const bf16x8*)(kb + r0 * 128 + (cb ^ ((r0 & 7) << 4)));
        bf16x8 kf1 = *(const bf16x8*)(kb + r1 * 128 + (cb ^ ((r1 & 7) << 4)));
        s0 = __builtin_amdgcn_mfma_f32_32x32x16_bf16(kf0, qf[s], s0, 0, 0, 0);
        s1 = __builtin_amdgcn_mfma_f32_32x32x16_bf16(kf1, qf[s], s1, 0, 0, 0);
      }
      __builtin_amdgcn_s_setprio(0);
      if (tt == dq) {  // causal mask on the diagonal tile
        const int qg = q0w + ql;
#pragma unroll
        for (int r = 0; r < 16; ++r) {
          const int kvl = (r & 3) + 8 * (r >> 2) + 4 * h;
          if (kv0 + kvl > qg) s0[r] = -3.0e38f;
          if (kv0 + 32 + kvl > qg) s1[r] = -3.0e38f;
        }
      }
      // lane-local online softmax (lane owns row q = ql across both h copies)
      float mx[16];
#pragma unroll
      for (int i = 0; i < 16; ++i) mx[i] = fmaxf(s0[i], s1[i]);
#pragma unroll
      for (int d = 8; d; d >>= 1)
#pragma unroll
        for (int i = 0; i < d; ++i) mx[i] = fmaxf(mx[i], mx[i + d]);
      const float tm = fmaxf(mx[0], __shfl_xor(mx[0], 32, 64));
      // defer-max: only rescale when the running max grew by > 4 (P bounded by 2^4)
      if (!__all(tm <= m + 4.0f)) {
        const float mnew = fmaxf(m, tm);
        const float fold = __builtin_amdgcn_exp2f(m - mnew);
        m = mnew;
        l *= fold;
#pragma unroll
        for (int i = 0; i < 16; ++i) { ot0[i] *= fold; ot1[i] *= fold; }
      }
#pragma unroll
      for (int i = 0; i < 16; ++i) {
        s0[i] = __builtin_amdgcn_exp2f(s0[i] - m);
        s1[i] = __builtin_amdgcn_exp2f(s1[i] - m);
      }
      float sm[16];
#pragma unroll
      for (int i = 0; i < 16; ++i) sm[i] = s0[i] + s1[i];
#pragma unroll
      for (int d = 8; d; d >>= 1)
#pragma unroll
        for (int i = 0; i < d; ++i) sm[i] += sm[i + d];
      l += sm[0] + __shfl_xor(sm[0], 32, 64);

      // pack P (f32 C-layout) -> bf16 B-fragments via lane^32 exchange
      u32 w0[8], w1[8];
#pragma unroll
      for (int mm = 0; mm < 8; ++mm) {
        asm("v_cvt_pk_bf16_f32 %0, %1, %2" : "=v"(w0[mm]) : "v"(s0[2 * mm]), "v"(s0[2 * mm + 1]));
        asm("v_cvt_pk_bf16_f32 %0, %1, %2" : "=v"(w1[mm]) : "v"(s1[2 * mm]), "v"(s1[2 * mm + 1]));
      }
      __builtin_amdgcn_s_setprio(1);
#pragma unroll
      for (int sb = 0; sb < 2; ++sb) {
#pragma unroll
        for (int t = 0; t < 2; ++t) {
          u32 a0 = sb ? w1[4 * t]     : w0[4 * t];
          u32 a1 = sb ? w1[4 * t + 1] : w0[4 * t + 1];
          u32 a2 = sb ? w1[4 * t + 2] : w0[4 * t + 2];
          u32 a3 = sb ? w1[4 * t + 3] : w0[4 * t + 3];
          u32 snd0 = hi ? a0 : a2;
          u32 snd1 = hi ? a1 : a3;
          u32 own0 = hi ? a2 : a0;
          u32 own1 = hi ? a3 : a1;
          u32 p0 = __shfl_xor(snd0, 32, 64);
          u32 p1 = __shfl_xor(snd1, 32, 64);
          union { u32 u[4]; bf16x8 v; } fr;
          fr.u[0] = hi ? p0 : own0;   // j0..3  <- h_src = 0
          fr.u[1] = hi ? p1 : own1;
          fr.u[2] = hi ? own0 : p0;   // j4..7  <- h_src = 1
          fr.u[3] = hi ? own1 : p1;
          const int s = sb * 2 + t;   // kv step: kv = 16s + 8h + j
          const int cb = 32 * s + 16 * h;
          const int r0 = ql, r1 = 32 + ql;
          bf16x8 vf0 = *(const bf16x8*)(vb + r0 * 128 + (cb ^ ((r0 & 7) << 4)));
          bf16x8 vf1 = *(const bf16x8*)(vb + r1 * 128 + (cb ^ ((r1 & 7) << 4)));
          ot0 = __builtin_amdgcn_mfma_f32_32x32x16_bf16(vf0, fr.v, ot0, 0, 0, 0);
          ot1 = __builtin_amdgcn_mfma_f32_32x32x16_bf16(vf1, fr.v, ot1, 0, 0, 0);
        }
      }
      __builtin_amdgcn_s_setprio(0);
    }
    __builtin_amdgcn_s_barrier();
    __builtin_amdgcn_sched_barrier(0);
  }
#undef STAGE

  // ---- combine wave pairs (par 1 -> par 0) through LDS: region qsub = [32 q][66 f32] ----
  float* R = (float*)(lds + qsub * 8448);
  if (par == 1) {
#pragma unroll
    for (int r = 0; r < 16; ++r) {
      const int dl = (r & 3) + 8 * (r >> 2) + 4 * h;
      R[ql * 66 + dl] = ot0[r];
      R[ql * 66 + 32 + dl] = ot1[r];
    }
    if (!hi) { R[ql * 66 + 64] = m; R[ql * 66 + 65] = l; }
  }
  __builtin_amdgcn_s_barrier();
  if (par == 1) return;

  const float m2 = R[ql * 66 + 64];
  const float l2 = R[ql * 66 + 65];
  const float M = fmaxf(m, m2);
  const float c1 = __builtin_amdgcn_exp2f(m - M);
  const float c2 = __builtin_amdgcn_exp2f(m2 - M);
  const float L = c1 * l + c2 * l2;
  const float inv = 1.0f / L;
  float of0[16], of1[16];
#pragma unroll
  for (int r = 0; r < 16; ++r) {
    const int dl = (r & 3) + 8 * (r >> 2) + 4 * h;
    of0[r] = (c1 * ot0[r] + c2 * R[ql * 66 + dl]) * inv;
    of1[r] = (c1 * ot1[r] + c2 * R[ql * 66 + 32 + dl]) * inv;
  }
  asm volatile("s_waitcnt lgkmcnt(0)" ::: "memory");
  __builtin_amdgcn_sched_barrier(0);

  // ---- epilogue: per-wave LDS transpose ([64 d][33 q] f32) -> coalesced 16B stores ----
  float* E = (float*)(lds + qsub * 8448);
#pragma unroll
  for (int r = 0; r < 16; ++r) {
    const int dl = (r & 3) + 8 * (r >> 2) + 4 * h;
    E[dl * 33 + ql] = of0[r];
    E[(dl + 32) * 33 + ql] = of1[r];
  }
  asm volatile("s_waitcnt lgkmcnt(0)" ::: "memory");
  __builtin_amdgcn_sched_barrier(0);
  const int bb = bh >> 4, hh = bh & 15;
  const int r2 = lane >> 3;          // row within 8
  const int c8 = (lane & 7) * 8;     // d-chunk start
#pragma unroll
  for (int g = 0; g < 4; ++g) {
    const int qrow = g * 8 + r2;
    union { u16 a[8]; bf16x8 v; } ov;
#pragma unroll
    for (int j = 0; j < 8; ++j) ov.a[j] = f2bf(E[(c8 + j) * 33 + qrow]);
    *(bf16x8*)(AO + (size_t)(bb * T_SEQ + q0 + qsub * 32 + qrow) * HID + hh * HD + c8) = ov.v;
  }
}

extern "C" void kernel_launch(void* const* d_in, const int* in_sizes, int n_in,
                              void* d_out, int out_size, void* d_ws, size_t ws_size,
                              hipStream_t stream) {
  const float* x      = (const float*)d_in[0];
  const float* w_attn = (const float*)d_in[1];
  const float* b_attn = (const float*)d_in[2];
  const float* w_proj = (const float*)d_in[3];
  const float* b_proj = (const float*)d_in[4];
  float* out = (float*)d_out;

  char* ws = (char*)d_ws;
  u16* xb   = (u16*)(ws);                       // 8 MB  (4096 x 1024)
  u16* wabT = (u16*)(ws + (size_t)(8  << 20));  // 6 MB  (3072 x 1024)
  u16* wpbT = (u16*)(ws + (size_t)(14 << 20));  // 2 MB  (1024 x 1024)
  u16* q    = (u16*)(ws + (size_t)(16 << 20));  // 8 MB  (B,H,T,D)
  u16* k    = (u16*)(ws + (size_t)(24 << 20));  // 8 MB  (B,H,T,D)
  u16* v    = (u16*)(ws + (size_t)(32 << 20));  // 8 MB  (B,H,D,T)  transposed!
  u16* ao   = (u16*)(ws + (size_t)(40 << 20));  // 8 MB  (B,T,C)

  prep_k<<<dim3(5120), dim3(256), 0, stream>>>(x, xb, w_attn, wabT, w_proj, wpbT);
  gemm_k<<<dim3(24, 32), dim3(512), 0, stream>>>(xb, wabT, b_attn, q, k, v);
  attn_k<<<dim3(512), dim3(512), 0, stream>>>(q, k, v, ao);
  gemm2_k<<<dim3(8, 64), dim3(512), 0, stream>>>(ao, wpbT, b_proj, out);
}